// Round 9
// baseline (88.981 us; speedup 1.0000x reference)
//
#include <hip/hip_runtime.h>

#define NUM_IND 1000
#define ROWPAD  40   // floats per padded LDS row (160 B): bank base = 8*(id&3)
#define MPW     16   // macros per wave (contiguous 128 KB span)
#define THREADS 512  // 8 waves/block, 1 block/CU

typedef float f4 __attribute__((ext_vector_type(4)));

// ONE fused kernel, 512 threads x 256 blocks (1 block/CU, 8 waves).
// vs R8: HALF the waves, DOUBLE the span -> 8 concurrent write streams
// per CU of 128 KB each (fill kernels sustain 7 TB/s with ~3 streams/CU).
// Phase 0: each wave loads ALL idx for its 16-macro span upfront
//          (16 coalesced 256 B loads -> 16 per-lane regs), before the build.
// Phase 1: build padded 1000x40 table in LDS (each thread: 2 industries).
// Phase 2: ZERO-LOAD gather: fully unrolled 16x8 shfl -> ds_read -> store.
//          Pure monotone ascending write stream per wave, no waits.
__global__ __launch_bounds__(THREADS) void fused_encoder_kernel(
    const int*   __restrict__ idx,   // [B]
    const float* __restrict__ vars,  // [1000,8]
    const float* __restrict__ W1,    // [8,16]
    const float* __restrict__ b1,    // [16]
    const float* __restrict__ W2,    // [16,32]
    const float* __restrict__ b2,    // [32]
    const float* __restrict__ emb,   // [1000,32]
    f4*          __restrict__ out4,  // [B*8]
    int nmacros,                     // total4 / 512
    int total4)                      // B*8
{
    __shared__ __align__(16) float table[NUM_IND * ROWPAD];  // 160,000 B

    const int tid  = threadIdx.x;
    const int lane = tid & 63;
    const int wave = blockIdx.x * (THREADS >> 6) + (tid >> 6);
    const int mbeg = wave * MPW;                  // contiguous span start
    const int last = nmacros - 1;

    // ---- phase 0: all idx for this wave's span, before the build ----
    int a[MPW];
#pragma unroll
    for (int q = 0; q < MPW; ++q)
        a[q] = idx[min(mbeg + q, last) * 64 + lane];   // clamped, branchless

    // ---- phase 1: build table; thread covers industries tid, tid+512 ----
    for (int t = tid; t < NUM_IND; t += THREADS) {
        float v[8];
#pragma unroll
        for (int k = 0; k < 8; ++k) v[k] = vars[t * 8 + k];

        float h[16];
#pragma unroll
        for (int j = 0; j < 16; ++j) {
            float acc = b1[j];
#pragma unroll
            for (int k = 0; k < 8; ++k) acc = fmaf(v[k], W1[k * 16 + j], acc);
            h[j] = fmaxf(acc, 0.0f);
        }

        const f4* embrow = (const f4*)(emb + t * 32);
        f4* tabrow = (f4*)(table + t * ROWPAD);
#pragma unroll
        for (int r = 0; r < 8; ++r) {             // 8 f4 chunks of 32 outputs
            const f4 e = embrow[r];
            f4 o;
#pragma unroll
            for (int q = 0; q < 4; ++q) {
                const int j = r * 4 + q;
                float acc = b2[j];
#pragma unroll
                for (int k = 0; k < 16; ++k) acc = fmaf(h[k], W2[k * 32 + j], acc);
                o[q] = acc + 0.1f * e[q];
            }
            tabrow[r] = o;
        }
    }
    __syncthreads();

    const f4* tab4 = (const f4*)table;            // padded: row stride 10 f4

    // ---- phase 2: zero-load gather over the wave's contiguous span ----
    if (mbeg + MPW <= nmacros) {                  // full span (common case)
#pragma unroll
        for (int q = 0; q < MPW; ++q) {
            const int base = (mbeg + q) * 512 + lane;
#pragma unroll
            for (int c = 0; c < 8; ++c) {
                // lane serves chunk c*64+lane -> example 8c+(lane>>3)
                const int id = __shfl(a[q], 8 * c + (lane >> 3), 64);
                out4[base + c * 64] = tab4[id * (ROWPAD / 4) + (lane & 7)];
            }
        }
    } else {                                      // partial span (generic B)
#pragma unroll
        for (int q = 0; q < MPW; ++q) {
            if (mbeg + q < nmacros) {
                const int base = (mbeg + q) * 512 + lane;
#pragma unroll
                for (int c = 0; c < 8; ++c) {
                    const int id = __shfl(a[q], 8 * c + (lane >> 3), 64);
                    out4[base + c * 64] = tab4[id * (ROWPAD / 4) + (lane & 7)];
                }
            }
        }
    }

    // ---- generic tail (elements beyond full macros); empty for B = 2^21 ----
    if (blockIdx.x == 0 && tid < 64) {
        for (int g = nmacros * 512 + lane; g < total4; g += 64) {
            const int id = idx[g >> 3];
            out4[g] = tab4[id * (ROWPAD / 4) + (g & 7)];
        }
    }
}

extern "C" void kernel_launch(void* const* d_in, const int* in_sizes, int n_in,
                              void* d_out, int out_size, void* d_ws, size_t ws_size,
                              hipStream_t stream) {
    const int*   idx  = (const int*)  d_in[0];  // [B] int32
    const float* vars = (const float*)d_in[1];  // [1000,8]
    const float* W1   = (const float*)d_in[2];  // [8,16]
    const float* b1   = (const float*)d_in[3];  // [16]
    const float* W2   = (const float*)d_in[4];  // [16,32]
    const float* b2   = (const float*)d_in[5];  // [32]
    const float* emb  = (const float*)d_in[6];  // [1000,32]

    f4* out4 = (f4*)d_out;                      // [B*8] 16B chunks
    const int B = in_sizes[0];
    const int total4  = B * 8;                  // 16,777,216 for B=2^21
    const int nmacros = total4 / 512;           // 32,768

    // 256 blocks x 512 threads = 2048 waves x 16 macros = 32,768 macros.
    fused_encoder_kernel<<<256, THREADS, 0, stream>>>(idx, vars, W1, b1, W2, b2,
                                                      emb, out4, nmacros, total4);
}

// Round 10
// 62.318 us; speedup vs baseline: 1.4278x; 1.4278x over previous
//
#include <hip/hip_runtime.h>
#include <hip/hip_fp16.h>

#define NUM_IND 1000
#define ROWH    36   // halfs per padded LDS row (72 B): bank rot = 18*id mod 32
#define MPW     4    // macros per wave (contiguous 32 KB span)
#define THREADS 1024

typedef float f4 __attribute__((ext_vector_type(4)));

// ONE fused kernel, 1024 threads x 512 blocks -> 2 blocks/CU, 32 waves/CU.
// vs R8: fp16 table (72,000 B padded) halves LDS so TWO blocks co-reside,
// DOUBLING store-side TLP (R9 showed gather is store-TLP-limited).
// Structure otherwise identical to R8 (the best so far):
//  Phase 0: wave loads ALL idx for its contiguous 4-macro span upfront.
//  Phase 1: build padded fp16 table in LDS (thread t -> industry t).
//  Phase 2: ZERO-LOAD gather: unrolled shfl -> ds_read_b64 -> cvt -> store;
//           each wave emits a pure monotone ascending 32 KB write stream.
__global__ __launch_bounds__(THREADS, 8) void fused_encoder_kernel(
    const int*   __restrict__ idx,   // [B]
    const float* __restrict__ vars,  // [1000,8]
    const float* __restrict__ W1,    // [8,16]
    const float* __restrict__ b1,    // [16]
    const float* __restrict__ W2,    // [16,32]
    const float* __restrict__ b2,    // [32]
    const float* __restrict__ emb,   // [1000,32]
    f4*          __restrict__ out4,  // [B*8]
    int nmacros,                     // total4 / 512
    int total4)                      // B*8
{
    __shared__ __align__(8) __half table[NUM_IND * ROWH];   // 72,000 B

    const int tid  = threadIdx.x;
    const int lane = tid & 63;
    const int wave = blockIdx.x * (THREADS >> 6) + (tid >> 6);
    const int mbeg = wave * MPW;                  // contiguous span start
    const int last = nmacros - 1;

    // ---- phase 0: all idx for this wave's span, before the build ----
    int a[MPW];
#pragma unroll
    for (int q = 0; q < MPW; ++q)
        a[q] = idx[min(mbeg + q, last) * 64 + lane];   // clamped, branchless

    // ---- phase 1: thread t computes industry t's 32 outputs (fp16) ----
    if (tid < NUM_IND) {
        float v[8];
#pragma unroll
        for (int k = 0; k < 8; ++k) v[k] = vars[tid * 8 + k];

        float h[16];
#pragma unroll
        for (int j = 0; j < 16; ++j) {
            float acc = b1[j];
#pragma unroll
            for (int k = 0; k < 8; ++k) acc = fmaf(v[k], W1[k * 16 + j], acc);
            h[j] = fmaxf(acc, 0.0f);
        }

        const f4* embrow = (const f4*)(emb + tid * 32);
        __half2* rowp = (__half2*)(table + tid * ROWH);
#pragma unroll
        for (int r = 0; r < 8; ++r) {             // 8 chunks of 4 outputs
            const f4 e = embrow[r];
            float o[4];
#pragma unroll
            for (int q = 0; q < 4; ++q) {
                const int j = r * 4 + q;
                float acc = b2[j];
#pragma unroll
                for (int k = 0; k < 16; ++k) acc = fmaf(h[k], W2[k * 32 + j], acc);
                o[q] = acc + 0.1f * e[q];
            }
            rowp[r * 2 + 0] = __floats2half2_rn(o[0], o[1]);
            rowp[r * 2 + 1] = __floats2half2_rn(o[2], o[3]);
        }
    }
    __syncthreads();

    // ---- phase 2: zero-load gather over the wave's contiguous span ----
    const char* tabb = (const char*)table;
    const int   coff = (lane & 7) * 8;            // 8B chunk within row

#pragma unroll
    for (int q = 0; q < MPW; ++q) {
        if (mbeg + q < nmacros) {
            const int base = (mbeg + q) * 512 + lane;
#pragma unroll
            for (int c = 0; c < 8; ++c) {
                // lane serves chunk c*64+lane -> example 8c+(lane>>3)
                const int id = __shfl(a[q], 8 * c + (lane >> 3), 64);
                const uint2 u = *(const uint2*)(tabb + id * 72 + coff);
                const __half2 h0 = *(const __half2*)&u.x;
                const __half2 h1 = *(const __half2*)&u.y;
                f4 o;
                o[0] = __low2float(h0); o[1] = __high2float(h0);
                o[2] = __low2float(h1); o[3] = __high2float(h1);
                out4[base + c * 64] = o;
            }
        }
    }

    // ---- generic tail (elements beyond full macros); empty for B = 2^21 ----
    if (blockIdx.x == 0 && tid < 64) {
        for (int g = nmacros * 512 + lane; g < total4; g += 64) {
            const int id = idx[g >> 3];
            const uint2 u = *(const uint2*)(tabb + id * 72 + (g & 7) * 8);
            const __half2 h0 = *(const __half2*)&u.x;
            const __half2 h1 = *(const __half2*)&u.y;
            f4 o;
            o[0] = __low2float(h0); o[1] = __high2float(h0);
            o[2] = __low2float(h1); o[3] = __high2float(h1);
            out4[g] = o;
        }
    }
}

extern "C" void kernel_launch(void* const* d_in, const int* in_sizes, int n_in,
                              void* d_out, int out_size, void* d_ws, size_t ws_size,
                              hipStream_t stream) {
    const int*   idx  = (const int*)  d_in[0];  // [B] int32
    const float* vars = (const float*)d_in[1];  // [1000,8]
    const float* W1   = (const float*)d_in[2];  // [8,16]
    const float* b1   = (const float*)d_in[3];  // [16]
    const float* W2   = (const float*)d_in[4];  // [16,32]
    const float* b2   = (const float*)d_in[5];  // [32]
    const float* emb  = (const float*)d_in[6];  // [1000,32]

    f4* out4 = (f4*)d_out;                      // [B*8] 16B chunks
    const int B = in_sizes[0];
    const int total4  = B * 8;                  // 16,777,216 for B=2^21
    const int nmacros = total4 / 512;           // 32,768

    // 512 blocks x 1024 threads = 8192 waves x 4 macros = 32,768 macros.
    fused_encoder_kernel<<<512, THREADS, 0, stream>>>(idx, vars, W1, b1, W2, b2,
                                                      emb, out4, nmacros, total4);
}

// Round 11
// 51.447 us; speedup vs baseline: 1.7296x; 1.2113x over previous
//
#include <hip/hip_runtime.h>

#define NUM_IND 1000
#define ROWPAD  40   // floats per padded LDS row (160 B): bank base = 8*(id&3)
#define MPW     8    // macros per wave (contiguous 64 KB span)

typedef float f4 __attribute__((ext_vector_type(4)));

// ONE fused kernel, 1024 threads x 256 blocks (1 block/CU, 16 waves).
// == measured optimum (R8, 51.3 us). Scan results around this point:
//    waves/CU {8,16,32} -> {89.0, 51.3, 62.3} us; block-interleaved
//    streams (R7) 62.6; per-iteration idx loads (R5) 62.9.
// Phase 0: each wave loads ALL idx for its contiguous 8-macro (64 KB) span
//          upfront: 8 coalesced 256 B loads -> 8 per-lane registers. These
//          complete under the build phase's MLP.
// Phase 1: build padded 1000x40 fp32 table in LDS (thread t -> industry t).
// Phase 2: ZERO-LOAD gather: fully unrolled 8x8 shfl -> ds_read_b128 ->
//          store. Each wave emits a pure, monotonically-ascending 64 KB
//          write stream (fill-kernel regime: no loads, no waits, no
//          branches mixed into the store stream).
__global__ __launch_bounds__(1024) void fused_encoder_kernel(
    const int*   __restrict__ idx,   // [B]
    const float* __restrict__ vars,  // [1000,8]
    const float* __restrict__ W1,    // [8,16]
    const float* __restrict__ b1,    // [16]
    const float* __restrict__ W2,    // [16,32]
    const float* __restrict__ b2,    // [32]
    const float* __restrict__ emb,   // [1000,32]
    f4*          __restrict__ out4,  // [B*8]
    int nmacros,                     // total4 / 512
    int total4)                      // B*8
{
    __shared__ __align__(16) float table[NUM_IND * ROWPAD];  // 160,000 B

    const int tid  = threadIdx.x;
    const int lane = tid & 63;
    const int wave = blockIdx.x * (blockDim.x >> 6) + (tid >> 6);
    const int mbeg = wave * MPW;                  // contiguous span start
    const int last = nmacros - 1;

    // ---- phase 0: all idx for this wave's span, before the build ----
    int a[MPW];
#pragma unroll
    for (int q = 0; q < MPW; ++q)
        a[q] = idx[min(mbeg + q, last) * 64 + lane];   // clamped, branchless

    // ---- phase 1: thread t computes industry t's 32 outputs ----
    if (tid < NUM_IND) {
        float v[8];
#pragma unroll
        for (int k = 0; k < 8; ++k) v[k] = vars[tid * 8 + k];

        float h[16];
#pragma unroll
        for (int j = 0; j < 16; ++j) {
            float acc = b1[j];
#pragma unroll
            for (int k = 0; k < 8; ++k) acc = fmaf(v[k], W1[k * 16 + j], acc);
            h[j] = fmaxf(acc, 0.0f);
        }

        const f4* embrow = (const f4*)(emb + tid * 32);
        f4* tabrow = (f4*)(table + tid * ROWPAD);
#pragma unroll
        for (int r = 0; r < 8; ++r) {             // 8 f4 chunks of 32 outputs
            const f4 e = embrow[r];
            f4 o;
#pragma unroll
            for (int q = 0; q < 4; ++q) {
                const int j = r * 4 + q;
                float acc = b2[j];
#pragma unroll
                for (int k = 0; k < 16; ++k) acc = fmaf(h[k], W2[k * 32 + j], acc);
                o[q] = acc + 0.1f * e[q];
            }
            tabrow[r] = o;
        }
    }
    __syncthreads();

    const f4* tab4 = (const f4*)table;            // padded: row stride 10 f4

    // ---- phase 2: zero-load gather over the wave's contiguous span ----
    if (mbeg + MPW <= nmacros) {                  // full span (common case)
#pragma unroll
        for (int q = 0; q < MPW; ++q) {
            const int base = (mbeg + q) * 512 + lane;
#pragma unroll
            for (int c = 0; c < 8; ++c) {
                // lane serves chunk c*64+lane -> example 8c+(lane>>3)
                const int id = __shfl(a[q], 8 * c + (lane >> 3), 64);
                out4[base + c * 64] = tab4[id * (ROWPAD / 4) + (lane & 7)];
            }
        }
    } else {                                      // partial span (generic B)
#pragma unroll
        for (int q = 0; q < MPW; ++q) {
            if (mbeg + q < nmacros) {
                const int base = (mbeg + q) * 512 + lane;
#pragma unroll
                for (int c = 0; c < 8; ++c) {
                    const int id = __shfl(a[q], 8 * c + (lane >> 3), 64);
                    out4[base + c * 64] = tab4[id * (ROWPAD / 4) + (lane & 7)];
                }
            }
        }
    }

    // ---- generic tail (elements beyond full macros); empty for B = 2^21 ----
    if (blockIdx.x == 0 && tid < 64) {
        for (int g = nmacros * 512 + lane; g < total4; g += 64) {
            const int id = idx[g >> 3];
            out4[g] = tab4[id * (ROWPAD / 4) + (g & 7)];
        }
    }
}

extern "C" void kernel_launch(void* const* d_in, const int* in_sizes, int n_in,
                              void* d_out, int out_size, void* d_ws, size_t ws_size,
                              hipStream_t stream) {
    const int*   idx  = (const int*)  d_in[0];  // [B] int32
    const float* vars = (const float*)d_in[1];  // [1000,8]
    const float* W1   = (const float*)d_in[2];  // [8,16]
    const float* b1   = (const float*)d_in[3];  // [16]
    const float* W2   = (const float*)d_in[4];  // [16,32]
    const float* b2   = (const float*)d_in[5];  // [32]
    const float* emb  = (const float*)d_in[6];  // [1000,32]

    f4* out4 = (f4*)d_out;                      // [B*8] 16B chunks
    const int B = in_sizes[0];
    const int total4  = B * 8;                  // 16,777,216 for B=2^21
    const int nmacros = total4 / 512;           // 32,768

    // 256 blocks x 1024 threads = 4096 waves x 8 macros = 32,768 macros.
    fused_encoder_kernel<<<256, 1024, 0, stream>>>(idx, vars, W1, b1, W2, b2,
                                                   emb, out4, nmacros, total4);
}